// Round 1
// baseline (417.174 us; speedup 1.0000x reference)
//
#include <hip/hip_runtime.h>

#define B_  64
#define K_  256
#define T_  64
#define DF_ 768
#define N_  1024

typedef __attribute__((ext_vector_type(8))) short bf16x8;
typedef __attribute__((ext_vector_type(4))) float f32x4;

__device__ __forceinline__ unsigned short bf_rne(float x) {
    unsigned u = __float_as_uint(x);
    unsigned r = u + 0x7fffu + ((u >> 16) & 1u);
    return (unsigned short)(r >> 16);
}

// ---------------------------------------------------------------------------
// prep_we: blocks [0,768): W[d][k] -> W_hi/W_lo [d][k], WT_hi [k][d]
//          blocks [768,1024): e[b][k][t] -> eT_hi/eT_lo [b][t][k]
// ---------------------------------------------------------------------------
__global__ __launch_bounds__(256) void prep_we(const float* __restrict__ W,
                                               const float* __restrict__ e,
                                               unsigned short* __restrict__ W_hi,
                                               unsigned short* __restrict__ W_lo,
                                               unsigned short* __restrict__ WT_hi,
                                               unsigned short* __restrict__ eT_hi,
                                               unsigned short* __restrict__ eT_lo) {
    int blk = blockIdx.x;
    if (blk < DF_) {
        int d = blk, k = threadIdx.x;
        float w = W[d * K_ + k];
        unsigned u = __float_as_uint(w);
        unsigned short hs = (unsigned short)(u >> 16);  // truncation: exact hi
        float hi = __uint_as_float(u & 0xffff0000u);
        W_hi[d * K_ + k]   = hs;
        W_lo[d * K_ + k]   = bf_rne(w - hi);
        WT_hi[k * DF_ + d] = hs;
    } else {
        int q = blk - DF_;            // [0,256)
        int b = q >> 2, kq = q & 3;
        int t = threadIdx.x & 63, ko = threadIdx.x >> 6;
        const float* eb = e + (size_t)b * K_ * T_;
        unsigned short* eh = eT_hi + (size_t)b * T_ * K_;
        unsigned short* el = eT_lo + (size_t)b * T_ * K_;
#pragma unroll
        for (int i = 0; i < 16; i++) {
            int k = kq * 64 + ko * 16 + i;
            float x = eb[k * T_ + t];            // coalesced over t
            unsigned u = __float_as_uint(x);
            unsigned short hs = (unsigned short)(u >> 16);
            float hi = __uint_as_float(u & 0xffff0000u);
            eh[t * K_ + k] = hs;
            el[t * K_ + k] = bf_rne(x - hi);
        }
    }
}

// ---------------------------------------------------------------------------
// gemm_g: gT[t][d] = sum_k e[k][t]*W[d][k]   (split-bf16, 3-pass MFMA)
// grid (DF/64, B) = 768 blocks, tile [64t x 64d], BK=32.
// Register-prefetch pipelined (T14): next K-step's global loads fly during
// the current step's barrier+MFMA.
// ---------------------------------------------------------------------------
__global__ __launch_bounds__(256, 3) void gemm_g(const unsigned short* __restrict__ eT_hi,
                                                 const unsigned short* __restrict__ eT_lo,
                                                 const unsigned short* __restrict__ W_hi,
                                                 const unsigned short* __restrict__ W_lo,
                                                 unsigned short* __restrict__ gT_hi,
                                                 unsigned short* __restrict__ gT_lo) {
    __shared__ unsigned short LeH[64 * 40], LeL[64 * 40];
    __shared__ unsigned short LwH[64 * 40], LwL[64 * 40];
    const int dblk = blockIdx.x * 64;
    const int b = blockIdx.y;
    const int tid = threadIdx.x;
    const int lane = tid & 63, w = tid >> 6, q = lane >> 4, l16 = lane & 15;

    const unsigned short* eh = eT_hi + (size_t)b * T_ * K_;
    const unsigned short* el = eT_lo + (size_t)b * T_ * K_;

    f32x4 acc[4];
#pragma unroll
    for (int i = 0; i < 4; i++) acc[i] = (f32x4)(0.f);

    const int tr = tid >> 2, c8 = (tid & 3) * 8;
    const unsigned short* ehp = eh + (size_t)tr * K_ + c8;
    const unsigned short* elp = el + (size_t)tr * K_ + c8;
    const unsigned short* whp = W_hi + (size_t)(dblk + tr) * K_ + c8;
    const unsigned short* wlp = W_lo + (size_t)(dblk + tr) * K_ + c8;

    struct GSet { uint4 eH, eL, wH, wL; };
    GSet A, Bv;

    auto gload = [&](GSet& S, int k0) {
        S.eH = *(const uint4*)&ehp[k0];
        S.eL = *(const uint4*)&elp[k0];
        S.wH = *(const uint4*)&whp[k0];
        S.wL = *(const uint4*)&wlp[k0];
    };
    auto gstore = [&](const GSet& S) {
        *(uint4*)&LeH[tr * 40 + c8] = S.eH;
        *(uint4*)&LeL[tr * 40 + c8] = S.eL;
        *(uint4*)&LwH[tr * 40 + c8] = S.wH;
        *(uint4*)&LwL[tr * 40 + c8] = S.wL;
    };
    auto gcomp = [&]() {
        bf16x8 aH[4], aL[4], bH, bL;
#pragma unroll
        for (int mt = 0; mt < 4; mt++) {
            aH[mt] = *(const bf16x8*)&LeH[(mt * 16 + l16) * 40 + q * 8];
            aL[mt] = *(const bf16x8*)&LeL[(mt * 16 + l16) * 40 + q * 8];
        }
        int dl = w * 16 + l16;
        bH = *(const bf16x8*)&LwH[dl * 40 + q * 8];
        bL = *(const bf16x8*)&LwL[dl * 40 + q * 8];
#pragma unroll
        for (int mt = 0; mt < 4; mt++) {
            acc[mt] = __builtin_amdgcn_mfma_f32_16x16x32_bf16(aH[mt], bH, acc[mt], 0, 0, 0);
            acc[mt] = __builtin_amdgcn_mfma_f32_16x16x32_bf16(aH[mt], bL, acc[mt], 0, 0, 0);
            acc[mt] = __builtin_amdgcn_mfma_f32_16x16x32_bf16(aL[mt], bH, acc[mt], 0, 0, 0);
        }
    };

    gload(A, 0);
    for (int k0 = 0; k0 < K_; k0 += 64) {
        gload(Bv, k0 + 32);       // prefetch next (always valid: max 224)
        gstore(A);
        __syncthreads();
        gcomp();
        __syncthreads();
        if (k0 + 64 < K_) gload(A, k0 + 64);
        gstore(Bv);
        __syncthreads();
        gcomp();
        __syncthreads();
    }

    unsigned short* gh = gT_hi + (size_t)b * T_ * DF_;
    unsigned short* gl = gT_lo + (size_t)b * T_ * DF_;
#pragma unroll
    for (int mt = 0; mt < 4; mt++)
#pragma unroll
        for (int r = 0; r < 4; r++) {
            float x = acc[mt][r];
            int t = mt * 16 + q * 4 + r;
            int d = dblk + w * 16 + l16;
            unsigned u = __float_as_uint(x);
            unsigned short hs = (unsigned short)(u >> 16);
            float hi = __uint_as_float(u & 0xffff0000u);
            gh[t * DF_ + d] = hs;
            gl[t * DF_ + d] = bf_rne(x - hi);
        }
}

// ---------------------------------------------------------------------------
// gemm_s: s[t][n] = sum_d g[d][t]*f[d][n]   (split-bf16, 3-pass)
// 512 blocks (XCD-swizzled), tile [64t x 128n], BK=32, 2 blocks/CU.
// f transposed+split on the fly; register-prefetch pipelined.
// ---------------------------------------------------------------------------
__global__ __launch_bounds__(256, 2) void gemm_s(const unsigned short* __restrict__ gT_hi,
                                                 const unsigned short* __restrict__ gT_lo,
                                                 const float* __restrict__ f,
                                                 float* __restrict__ s) {
    __shared__ unsigned short LgH[64 * 40], LgL[64 * 40];
    __shared__ unsigned LfH[128 * 20], LfL[128 * 20];   // u32 = packed bf16 (d,d+1)

    const int flat = blockIdx.x;                  // 512 blocks
    const int b    = (flat & 7) * 8 + ((flat >> 3) & 7);
    const int nblk = (flat >> 6) * 128;
    const int tid = threadIdx.x;
    const int lane = tid & 63, w = tid >> 6, q = lane >> 4, l16 = lane & 15;

    const unsigned short* gh = gT_hi + (size_t)b * T_ * DF_;
    const unsigned short* gl = gT_lo + (size_t)b * T_ * DF_;

    f32x4 acc[4][2];
#pragma unroll
    for (int i = 0; i < 4; i++)
#pragma unroll
        for (int j = 0; j < 2; j++) acc[i][j] = (f32x4)(0.f);

    const int dp  = tid >> 4;          // d-pair 0..15
    const int nb  = (tid & 15) * 8;    // 8 consecutive n per thread
    const int rot = tid & 7;
    const int tr = tid >> 2, c8 = (tid & 3) * 8;

    const float* fbase = f + ((size_t)b * DF_ + dp * 2) * N_ + nblk + nb;
    const unsigned short* ghp = gh + (size_t)tr * DF_ + c8;
    const unsigned short* glp = gl + (size_t)tr * DF_ + c8;

    struct FSet { float4 x0, x1, y0, y1; uint4 gH, gL; };
    FSet A, Bv;

    auto sload = [&](FSet& S, int d0) {
        const float* fp = fbase + (size_t)d0 * N_;
        S.x0 = *(const float4*)&fp[0];
        S.x1 = *(const float4*)&fp[4];
        S.y0 = *(const float4*)&fp[N_ + 0];
        S.y1 = *(const float4*)&fp[N_ + 4];
        S.gH = *(const uint4*)&ghp[d0];
        S.gL = *(const uint4*)&glp[d0];
    };
    auto sstore = [&](const FSet& S) {
        *(uint4*)&LgH[tr * 40 + c8] = S.gH;
        *(uint4*)&LgL[tr * 40 + c8] = S.gL;
        const float xs[8] = {S.x0.x, S.x0.y, S.x0.z, S.x0.w, S.x1.x, S.x1.y, S.x1.z, S.x1.w};
        const float ys[8] = {S.y0.x, S.y0.y, S.y0.z, S.y0.w, S.y1.x, S.y1.y, S.y1.z, S.y1.w};
#pragma unroll
        for (int jj = 0; jj < 8; jj++) {
            int j = (jj + rot) & 7;            // lane-rotated: kills bank conflicts
            unsigned bx = __float_as_uint(xs[j]);
            unsigned by = __float_as_uint(ys[j]);
            unsigned hp = (bx >> 16) | (by & 0xffff0000u);
            float lx = xs[j] - __uint_as_float(bx & 0xffff0000u);
            float ly = ys[j] - __uint_as_float(by & 0xffff0000u);
            unsigned lp = (__float_as_uint(lx) >> 16) | (__float_as_uint(ly) & 0xffff0000u);
            LfH[(nb + j) * 20 + dp] = hp;
            LfL[(nb + j) * 20 + dp] = lp;
        }
    };
    auto scomp = [&]() {
        bf16x8 aH[4], aL[4], bH[2], bL[2];
#pragma unroll
        for (int mt = 0; mt < 4; mt++) {
            aH[mt] = *(const bf16x8*)&LgH[(mt * 16 + l16) * 40 + q * 8];
            aL[mt] = *(const bf16x8*)&LgL[(mt * 16 + l16) * 40 + q * 8];
        }
#pragma unroll
        for (int nt = 0; nt < 2; nt++) {
            int nl = w * 32 + nt * 16 + l16;
            bH[nt] = *(const bf16x8*)&((const unsigned short*)LfH)[nl * 40 + q * 8];
            bL[nt] = *(const bf16x8*)&((const unsigned short*)LfL)[nl * 40 + q * 8];
        }
#pragma unroll
        for (int mt = 0; mt < 4; mt++)
#pragma unroll
            for (int nt = 0; nt < 2; nt++) {
                acc[mt][nt] = __builtin_amdgcn_mfma_f32_16x16x32_bf16(aH[mt], bH[nt], acc[mt][nt], 0, 0, 0);
                acc[mt][nt] = __builtin_amdgcn_mfma_f32_16x16x32_bf16(aH[mt], bL[nt], acc[mt][nt], 0, 0, 0);
                acc[mt][nt] = __builtin_amdgcn_mfma_f32_16x16x32_bf16(aL[mt], bH[nt], acc[mt][nt], 0, 0, 0);
            }
    };

    sload(A, 0);
    for (int d0 = 0; d0 < DF_; d0 += 64) {
        sload(Bv, d0 + 32);       // always valid (max 736)
        sstore(A);
        __syncthreads();
        scomp();
        __syncthreads();
        if (d0 + 64 < DF_) sload(A, d0 + 64);
        sstore(Bv);
        __syncthreads();
        scomp();
        __syncthreads();
    }

    float* sb = s + (size_t)b * T_ * N_;
#pragma unroll
    for (int mt = 0; mt < 4; mt++)
#pragma unroll
        for (int nt = 0; nt < 2; nt++)
#pragma unroll
            for (int r = 0; r < 4; r++) {
                int t = mt * 16 + q * 4 + r;
                int n = nblk + w * 32 + nt * 16 + l16;
                sb[(size_t)t * N_ + n] = acc[mt][nt][r];
            }
}

// ---------------------------------------------------------------------------
// softmax over n -> bf16 alpha.  One wave per row: no LDS, no barriers.
// grid = B*T/4 blocks of 256 threads (4 independent waves).
// ---------------------------------------------------------------------------
__global__ __launch_bounds__(256) void softmax_k(const float* __restrict__ s,
                                                 unsigned short* __restrict__ alpha,
                                                 const float* __restrict__ gptr) {
    const float g = gptr[0];
    const int row_id = blockIdx.x * 4 + (threadIdx.x >> 6);
    const int lane = threadIdx.x & 63;
    const float* row = s + (size_t)row_id * N_;
    unsigned short* arow = alpha + (size_t)row_id * N_;

    float4 x[4];
#pragma unroll
    for (int i = 0; i < 4; i++) {
        x[i] = *(const float4*)(row + i * 256 + lane * 4);   // perfectly coalesced
        x[i].x *= g; x[i].y *= g; x[i].z *= g; x[i].w *= g;
    }
    float m = x[0].x;
#pragma unroll
    for (int i = 0; i < 4; i++)
        m = fmaxf(m, fmaxf(fmaxf(x[i].x, x[i].y), fmaxf(x[i].z, x[i].w)));
#pragma unroll
    for (int off = 32; off > 0; off >>= 1) m = fmaxf(m, __shfl_xor(m, off, 64));

    float ev[16];
    float sum = 0.f;
#pragma unroll
    for (int i = 0; i < 4; i++) {
        ev[i * 4 + 0] = __expf(x[i].x - m);
        ev[i * 4 + 1] = __expf(x[i].y - m);
        ev[i * 4 + 2] = __expf(x[i].z - m);
        ev[i * 4 + 3] = __expf(x[i].w - m);
        sum += ev[i * 4 + 0] + ev[i * 4 + 1] + ev[i * 4 + 2] + ev[i * 4 + 3];
    }
#pragma unroll
    for (int off = 32; off > 0; off >>= 1) sum += __shfl_xor(sum, off, 64);
    float inv = 1.f / sum;
#pragma unroll
    for (int i = 0; i < 4; i++) {
        unsigned p0 = (unsigned)bf_rne(ev[i * 4 + 0] * inv) | ((unsigned)bf_rne(ev[i * 4 + 1] * inv) << 16);
        unsigned p1 = (unsigned)bf_rne(ev[i * 4 + 2] * inv) | ((unsigned)bf_rne(ev[i * 4 + 3] * inv) << 16);
        uint2 o; o.x = p0; o.y = p1;
        *(uint2*)&arow[i * 256 + lane * 4] = o;
    }
}

// ---------------------------------------------------------------------------
// gemm_h: hT[t][d] = sum_n f[d][n]*alpha[t][n]   (plain bf16)
// grid (DF/64, B) = 768 blocks, tile [64d x 64t], BK=64.  Pipelined.
// ---------------------------------------------------------------------------
__global__ __launch_bounds__(256, 3) void gemm_h(const float* __restrict__ f,
                                                 const unsigned short* __restrict__ alpha,
                                                 unsigned short* __restrict__ hT) {
    __shared__ unsigned short Lf[64 * 72];
    __shared__ unsigned short La[64 * 72];
    const int dblk = blockIdx.x * 64;
    const int b = blockIdx.y;
    const int tid = threadIdx.x;
    const int lane = tid & 63, w = tid >> 6, q = lane >> 4, l16 = lane & 15;

    const float* fb = f + (size_t)b * DF_ * N_;
    const unsigned short* ab = alpha + (size_t)b * T_ * N_;

    f32x4 acc[4];
#pragma unroll
    for (int i = 0; i < 4; i++) acc[i] = (f32x4)(0.f);

    const int fr_ = tid >> 2, fc = tid & 3;
    const float* frbase = fb + (size_t)(dblk + fr_) * N_ + fc * 16;
    const int ar = tid >> 2, ac = (tid & 3) * 16;   // == original l=0/1 mapping
    const unsigned short* abase = ab + (size_t)ar * N_ + ac;

    struct HSet { float4 f0, f1, f2, f3; uint4 a0, a1; };
    HSet A, Bv;

    auto hload = [&](HSet& S, int n0) {
        const float* fp = frbase + n0;
        S.f0 = *(const float4*)&fp[0];
        S.f1 = *(const float4*)&fp[4];
        S.f2 = *(const float4*)&fp[8];
        S.f3 = *(const float4*)&fp[12];
        S.a0 = *(const uint4*)&abase[n0];
        S.a1 = *(const uint4*)&abase[n0 + 8];
    };
    auto hstore = [&](const HSet& S) {
        const float4 fx[4] = {S.f0, S.f1, S.f2, S.f3};
#pragma unroll
        for (int i = 0; i < 4; i++) {
            float4 x = fx[i];
            unsigned p0 = (unsigned)bf_rne(x.x) | ((unsigned)bf_rne(x.y) << 16);
            unsigned p1 = (unsigned)bf_rne(x.z) | ((unsigned)bf_rne(x.w) << 16);
            uint2 o; o.x = p0; o.y = p1;
            *(uint2*)&Lf[fr_ * 72 + fc * 16 + i * 4] = o;
        }
        *(uint4*)&La[ar * 72 + ac] = S.a0;
        *(uint4*)&La[ar * 72 + ac + 8] = S.a1;
    };
    auto hcomp = [&]() {
        bf16x8 af[2], bb[4][2];
#pragma unroll
        for (int kk = 0; kk < 2; kk++)
            af[kk] = *(const bf16x8*)&Lf[(w * 16 + l16) * 72 + kk * 32 + q * 8];
#pragma unroll
        for (int nt = 0; nt < 4; nt++)
#pragma unroll
            for (int kk = 0; kk < 2; kk++)
                bb[nt][kk] = *(const bf16x8*)&La[(nt * 16 + l16) * 72 + kk * 32 + q * 8];
#pragma unroll
        for (int nt = 0; nt < 4; nt++)
#pragma unroll
            for (int kk = 0; kk < 2; kk++)
                acc[nt] = __builtin_amdgcn_mfma_f32_16x16x32_bf16(af[kk], bb[nt][kk], acc[nt], 0, 0, 0);
    };

    hload(A, 0);
    for (int n0 = 0; n0 < N_; n0 += 128) {
        hload(Bv, n0 + 64);        // always valid (max 960)
        hstore(A);
        __syncthreads();
        hcomp();
        __syncthreads();
        if (n0 + 128 < N_) hload(A, n0 + 128);
        hstore(Bv);
        __syncthreads();
        hcomp();
        __syncthreads();
    }

    unsigned short* hb = hT + (size_t)b * T_ * DF_;
#pragma unroll
    for (int nt = 0; nt < 4; nt++)
#pragma unroll
        for (int r = 0; r < 4; r++) {
            int d = dblk + w * 16 + q * 4 + r;
            int t = nt * 16 + l16;
            hb[(size_t)t * DF_ + d] = bf_rne(acc[nt][r]);
        }
}

// ---------------------------------------------------------------------------
// gemm_c: c[k][t] = sum_d W[d][k]*h[d][t] + bias[k]   (plain bf16)
// grid (K/64, B) = 256 blocks (1/CU!), tile [64k x 64t], BK=64.  Pipelined —
// with one block per CU the register prefetch is the only latency hiding.
// ---------------------------------------------------------------------------
__global__ __launch_bounds__(256, 2) void gemm_c(const unsigned short* __restrict__ WT_hi,
                                                 const unsigned short* __restrict__ hT,
                                                 const float* __restrict__ bias,
                                                 float* __restrict__ c) {
    __shared__ unsigned short LW[64 * 72];
    __shared__ unsigned short Lh[64 * 72];
    const int kblk = blockIdx.x * 64;
    const int b = blockIdx.y;
    const int tid = threadIdx.x;
    const int lane = tid & 63, w = tid >> 6, q = lane >> 4, l16 = lane & 15;

    const unsigned short* hb = hT + (size_t)b * T_ * DF_;

    f32x4 acc[4];
#pragma unroll
    for (int i = 0; i < 4; i++) acc[i] = (f32x4)(0.f);

    const int r_ = tid >> 2, cc = (tid & 3) * 16;
    const unsigned short* wbase = WT_hi + (size_t)(kblk + r_) * DF_ + cc;
    const unsigned short* hbase = hb + (size_t)r_ * DF_ + cc;

    struct CSet { uint4 w0, w1, h0, h1; };
    CSet A, Bv;

    auto cload = [&](CSet& S, int d0) {
        S.w0 = *(const uint4*)&wbase[d0];
        S.w1 = *(const uint4*)&wbase[d0 + 8];
        S.h0 = *(const uint4*)&hbase[d0];
        S.h1 = *(const uint4*)&hbase[d0 + 8];
    };
    auto cstore = [&](const CSet& S) {
        *(uint4*)&LW[r_ * 72 + cc]     = S.w0;
        *(uint4*)&LW[r_ * 72 + cc + 8] = S.w1;
        *(uint4*)&Lh[r_ * 72 + cc]     = S.h0;
        *(uint4*)&Lh[r_ * 72 + cc + 8] = S.h1;
    };
    auto ccomp = [&]() {
        bf16x8 aw[2], bh[4][2];
#pragma unroll
        for (int kk = 0; kk < 2; kk++)
            aw[kk] = *(const bf16x8*)&LW[(w * 16 + l16) * 72 + kk * 32 + q * 8];
#pragma unroll
        for (int nt = 0; nt < 4; nt++)
#pragma unroll
            for (int kk = 0; kk < 2; kk++)
                bh[nt][kk] = *(const bf16x8*)&Lh[(nt * 16 + l16) * 72 + kk * 32 + q * 8];
#pragma unroll
        for (int nt = 0; nt < 4; nt++)
#pragma unroll
            for (int kk = 0; kk < 2; kk++)
                acc[nt] = __builtin_amdgcn_mfma_f32_16x16x32_bf16(aw[kk], bh[nt][kk], acc[nt], 0, 0, 0);
    };

    cload(A, 0);
    for (int d0 = 0; d0 < DF_; d0 += 128) {
        cload(Bv, d0 + 64);        // always valid (max 704)
        cstore(A);
        __syncthreads();
        ccomp();
        __syncthreads();
        if (d0 + 128 < DF_) cload(A, d0 + 128);
        cstore(Bv);
        __syncthreads();
        ccomp();
        __syncthreads();
    }

    float* cb = c + (size_t)b * K_ * T_;
#pragma unroll
    for (int nt = 0; nt < 4; nt++)
#pragma unroll
        for (int r = 0; r < 4; r++) {
            int k = kblk + w * 16 + q * 4 + r;
            int t = nt * 16 + l16;
            cb[(size_t)k * T_ + t] = acc[nt][r] + bias[k];
        }
}

// ---------------------------------------------------------------------------
// cos_k: cos[b,i,j] = <c[:,i], e[:,j]> / (|c[:,i]| |e[:,j]|)
// grid (T/4, B), 256 threads: wave iq handles row i = bx*4+iq.
// ---------------------------------------------------------------------------
__global__ __launch_bounds__(256) void cos_k(const float* __restrict__ c,
                                             const float* __restrict__ e,
                                             float* __restrict__ out) {
    const int iq = threadIdx.x >> 6;
    const int i = blockIdx.x * 4 + iq;
    const int b = blockIdx.y;
    const int j = threadIdx.x & 63;
    const float* cb = c + (size_t)b * K_ * T_;
    const float* eb = e + (size_t)b * K_ * T_;

    float dot = 0.f, se = 0.f, sc = 0.f;
#pragma unroll 8
    for (int k = 0; k < K_; k++) {
        float cv = cb[(size_t)k * T_ + i];
        float ev = eb[(size_t)k * T_ + j];
        dot += cv * ev;
        se  += ev * ev;
        sc  += cv * cv;
    }
    out[((size_t)b * T_ + i) * T_ + j] = dot * rsqrtf(sc * se);
}

// ---------------------------------------------------------------------------
extern "C" void kernel_launch(void* const* d_in, const int* in_sizes, int n_in,
                              void* d_out, int out_size, void* d_ws, size_t ws_size,
                              hipStream_t stream) {
    const float* e     = (const float*)d_in[0];  // [B,K,T]
    const float* f     = (const float*)d_in[1];  // [B,DF,N]
    const float* gamma = (const float*)d_in[2];
    const float* W     = (const float*)d_in[3];  // [DF,K]
    const float* bias  = (const float*)d_in[4];  // [K]
    float* out = (float*)d_out;                  // [B,T,T]

    char* p = (char*)d_ws;
    unsigned short* W_hi  = (unsigned short*)p; p += (size_t)DF_ * K_ * 2;
    unsigned short* W_lo  = (unsigned short*)p; p += (size_t)DF_ * K_ * 2;
    unsigned short* WT_hi = (unsigned short*)p; p += (size_t)DF_ * K_ * 2;
    unsigned short* eT_hi = (unsigned short*)p; p += (size_t)B_ * T_ * K_ * 2;
    unsigned short* eT_lo = (unsigned short*)p; p += (size_t)B_ * T_ * K_ * 2;
    unsigned short* gT_hi = (unsigned short*)p; p += (size_t)B_ * T_ * DF_ * 2;
    unsigned short* gT_lo = (unsigned short*)p; p += (size_t)B_ * T_ * DF_ * 2;
    float*          s     = (float*)p;          p += (size_t)B_ * T_ * N_ * 4;
    unsigned short* alpha = (unsigned short*)p; p += (size_t)B_ * T_ * N_ * 2;
    unsigned short* hT    = (unsigned short*)p; p += (size_t)B_ * T_ * DF_ * 2;
    float*          c     = (float*)p;          p += (size_t)B_ * K_ * T_ * 4;

    prep_we <<<dim3(DF_ + 256),      256, 0, stream>>>(W, e, W_hi, W_lo, WT_hi, eT_hi, eT_lo);
    gemm_g  <<<dim3(DF_ / 64, B_),   256, 0, stream>>>(eT_hi, eT_lo, W_hi, W_lo, gT_hi, gT_lo);
    gemm_s  <<<dim3(512),            256, 0, stream>>>(gT_hi, gT_lo, f, s);
    softmax_k<<<dim3(B_ * T_ / 4),   256, 0, stream>>>(s, alpha, gamma);
    gemm_h  <<<dim3(DF_ / 64, B_),   256, 0, stream>>>(f, alpha, hT);
    gemm_c  <<<dim3(K_ / 64, B_),    256, 0, stream>>>(WT_hi, hT, bias, c);
    cos_k   <<<dim3(T_ / 4, B_),     256, 0, stream>>>(c, e, out);
}

// Round 2
// 374.950 us; speedup vs baseline: 1.1126x; 1.1126x over previous
//
#include <hip/hip_runtime.h>

#define B_  64
#define K_  256
#define T_  64
#define DF_ 768
#define N_  1024

typedef __attribute__((ext_vector_type(8))) short bf16x8;
typedef __attribute__((ext_vector_type(4))) float f32x4;

__device__ __forceinline__ unsigned short bf_rne(float x) {
    unsigned u = __float_as_uint(x);
    unsigned r = u + 0x7fffu + ((u >> 16) & 1u);
    return (unsigned short)(r >> 16);
}

// ---------------------------------------------------------------------------
// prep_we: blocks [0,768): W[d][k] -> W_hi/W_lo [d][k], WT_hi [k][d]
//          blocks [768,1024): e[b][k][t] -> eT_hi/eT_lo [b][t][k]
// ---------------------------------------------------------------------------
__global__ __launch_bounds__(256) void prep_we(const float* __restrict__ W,
                                               const float* __restrict__ e,
                                               unsigned short* __restrict__ W_hi,
                                               unsigned short* __restrict__ W_lo,
                                               unsigned short* __restrict__ WT_hi,
                                               unsigned short* __restrict__ eT_hi,
                                               unsigned short* __restrict__ eT_lo) {
    int blk = blockIdx.x;
    if (blk < DF_) {
        int d = blk, k = threadIdx.x;
        float w = W[d * K_ + k];
        unsigned u = __float_as_uint(w);
        unsigned short hs = (unsigned short)(u >> 16);  // truncation: exact hi
        float hi = __uint_as_float(u & 0xffff0000u);
        W_hi[d * K_ + k]   = hs;
        W_lo[d * K_ + k]   = bf_rne(w - hi);
        WT_hi[k * DF_ + d] = hs;
    } else {
        int q = blk - DF_;            // [0,256)
        int b = q >> 2, kq = q & 3;
        int t = threadIdx.x & 63, ko = threadIdx.x >> 6;
        const float* eb = e + (size_t)b * K_ * T_;
        unsigned short* eh = eT_hi + (size_t)b * T_ * K_;
        unsigned short* el = eT_lo + (size_t)b * T_ * K_;
#pragma unroll
        for (int i = 0; i < 16; i++) {
            int k = kq * 64 + ko * 16 + i;
            float x = eb[k * T_ + t];            // coalesced over t
            unsigned u = __float_as_uint(x);
            unsigned short hs = (unsigned short)(u >> 16);
            float hi = __uint_as_float(u & 0xffff0000u);
            eh[t * K_ + k] = hs;
            el[t * K_ + k] = bf_rne(x - hi);
        }
    }
}

// ---------------------------------------------------------------------------
// gemm_g: gT[t][d] = sum_k e[k][t]*W[d][k]   (split-bf16, 3-pass MFMA)
// grid (DF/64, B) = 768 blocks, tile [64t x 64d], BK=32.  (round-0 form)
// ---------------------------------------------------------------------------
__global__ __launch_bounds__(256, 2) void gemm_g(const unsigned short* __restrict__ eT_hi,
                                                 const unsigned short* __restrict__ eT_lo,
                                                 const unsigned short* __restrict__ W_hi,
                                                 const unsigned short* __restrict__ W_lo,
                                                 unsigned short* __restrict__ gT_hi,
                                                 unsigned short* __restrict__ gT_lo) {
    __shared__ unsigned short LeH[64 * 40], LeL[64 * 40];
    __shared__ unsigned short LwH[64 * 40], LwL[64 * 40];
    const int dblk = blockIdx.x * 64;
    const int b = blockIdx.y;
    const int tid = threadIdx.x;
    const int lane = tid & 63, w = tid >> 6, q = lane >> 4, l16 = lane & 15;

    const unsigned short* eh = eT_hi + (size_t)b * T_ * K_;
    const unsigned short* el = eT_lo + (size_t)b * T_ * K_;

    f32x4 acc[4];
#pragma unroll
    for (int i = 0; i < 4; i++) acc[i] = (f32x4)(0.f);

    const int tr = tid >> 2, c8 = (tid & 3) * 8;
    for (int k0 = 0; k0 < K_; k0 += 32) {
        *(uint4*)&LeH[tr * 40 + c8] = *(const uint4*)&eh[tr * K_ + k0 + c8];
        *(uint4*)&LeL[tr * 40 + c8] = *(const uint4*)&el[tr * K_ + k0 + c8];
        *(uint4*)&LwH[tr * 40 + c8] = *(const uint4*)&W_hi[(size_t)(dblk + tr) * K_ + k0 + c8];
        *(uint4*)&LwL[tr * 40 + c8] = *(const uint4*)&W_lo[(size_t)(dblk + tr) * K_ + k0 + c8];
        __syncthreads();
        bf16x8 aH[4], aL[4], bH, bL;
#pragma unroll
        for (int mt = 0; mt < 4; mt++) {
            aH[mt] = *(const bf16x8*)&LeH[(mt * 16 + l16) * 40 + q * 8];
            aL[mt] = *(const bf16x8*)&LeL[(mt * 16 + l16) * 40 + q * 8];
        }
        int dl = w * 16 + l16;
        bH = *(const bf16x8*)&LwH[dl * 40 + q * 8];
        bL = *(const bf16x8*)&LwL[dl * 40 + q * 8];
#pragma unroll
        for (int mt = 0; mt < 4; mt++) {
            acc[mt] = __builtin_amdgcn_mfma_f32_16x16x32_bf16(aH[mt], bH, acc[mt], 0, 0, 0);
            acc[mt] = __builtin_amdgcn_mfma_f32_16x16x32_bf16(aH[mt], bL, acc[mt], 0, 0, 0);
            acc[mt] = __builtin_amdgcn_mfma_f32_16x16x32_bf16(aL[mt], bH, acc[mt], 0, 0, 0);
        }
        __syncthreads();
    }

    unsigned short* gh = gT_hi + (size_t)b * T_ * DF_;
    unsigned short* gl = gT_lo + (size_t)b * T_ * DF_;
#pragma unroll
    for (int mt = 0; mt < 4; mt++)
#pragma unroll
        for (int r = 0; r < 4; r++) {
            float x = acc[mt][r];
            int t = mt * 16 + q * 4 + r;
            int d = dblk + w * 16 + l16;
            unsigned u = __float_as_uint(x);
            unsigned short hs = (unsigned short)(u >> 16);
            float hi = __uint_as_float(u & 0xffff0000u);
            gh[t * DF_ + d] = hs;
            gl[t * DF_ + d] = bf_rne(x - hi);
        }
}

// ---------------------------------------------------------------------------
// gemm_s: s[t][n] = sum_d g[d][t]*f[d][n]   (split-bf16, 3-pass)
// 512 blocks (XCD-swizzled), tile [64t x 128n], BK=32, 2 blocks/CU.
// DOUBLE-BUFFERED LDS, one barrier per K-step: next-tile global loads are
// issued before compute and consumed (ds_write) after it, so HBM latency
// hides under MFMA instead of being drained at the barrier.
// ---------------------------------------------------------------------------
__global__ __launch_bounds__(256, 2) void gemm_s(const unsigned short* __restrict__ gT_hi,
                                                 const unsigned short* __restrict__ gT_lo,
                                                 const float* __restrict__ f,
                                                 float* __restrict__ s) {
    __shared__ unsigned short LgH[2][64 * 40], LgL[2][64 * 40];
    __shared__ unsigned LfH[2][128 * 20], LfL[2][128 * 20];   // u32 = packed bf16 (d,d+1)

    const int flat = blockIdx.x;                  // 512 blocks
    const int b    = (flat & 7) * 8 + ((flat >> 3) & 7);
    const int nblk = (flat >> 6) * 128;
    const int tid = threadIdx.x;
    const int lane = tid & 63, w = tid >> 6, q = lane >> 4, l16 = lane & 15;

    const unsigned short* gh = gT_hi + (size_t)b * T_ * DF_;
    const unsigned short* gl = gT_lo + (size_t)b * T_ * DF_;

    f32x4 acc[4][2];
#pragma unroll
    for (int i = 0; i < 4; i++)
#pragma unroll
        for (int j = 0; j < 2; j++) acc[i][j] = (f32x4)(0.f);

    const int dp  = tid >> 4;          // d-pair 0..15
    const int nb  = (tid & 15) * 8;    // 8 consecutive n per thread
    const int rot = tid & 7;
    const int tr = tid >> 2, c8 = (tid & 3) * 8;

    const float* fbase = f + ((size_t)b * DF_ + dp * 2) * N_ + nblk + nb;
    const unsigned short* ghp = gh + (size_t)tr * DF_ + c8;
    const unsigned short* glp = gl + (size_t)tr * DF_ + c8;

    float4 px0, px1, py0, py1;
    uint4 pgH, pgL;

    auto sload = [&](int d0) {
        const float* fp = fbase + (size_t)d0 * N_;
        px0 = *(const float4*)&fp[0];
        px1 = *(const float4*)&fp[4];
        py0 = *(const float4*)&fp[N_ + 0];
        py1 = *(const float4*)&fp[N_ + 4];
        pgH = *(const uint4*)&ghp[d0];
        pgL = *(const uint4*)&glp[d0];
    };
    auto sstore = [&](int buf) {
        *(uint4*)&LgH[buf][tr * 40 + c8] = pgH;
        *(uint4*)&LgL[buf][tr * 40 + c8] = pgL;
        const float xs[8] = {px0.x, px0.y, px0.z, px0.w, px1.x, px1.y, px1.z, px1.w};
        const float ys[8] = {py0.x, py0.y, py0.z, py0.w, py1.x, py1.y, py1.z, py1.w};
#pragma unroll
        for (int jj = 0; jj < 8; jj++) {
            int j = (jj + rot) & 7;            // lane-rotated: kills bank conflicts
            unsigned bx = __float_as_uint(xs[j]);
            unsigned by = __float_as_uint(ys[j]);
            unsigned hp = (bx >> 16) | (by & 0xffff0000u);
            float lx = xs[j] - __uint_as_float(bx & 0xffff0000u);
            float ly = ys[j] - __uint_as_float(by & 0xffff0000u);
            unsigned lp = (__float_as_uint(lx) >> 16) | (__float_as_uint(ly) & 0xffff0000u);
            LfH[buf][(nb + j) * 20 + dp] = hp;
            LfL[buf][(nb + j) * 20 + dp] = lp;
        }
    };
    auto scomp = [&](int buf) {
        bf16x8 aH[4], aL[4], bH[2], bL[2];
#pragma unroll
        for (int mt = 0; mt < 4; mt++) {
            aH[mt] = *(const bf16x8*)&LgH[buf][(mt * 16 + l16) * 40 + q * 8];
            aL[mt] = *(const bf16x8*)&LgL[buf][(mt * 16 + l16) * 40 + q * 8];
        }
#pragma unroll
        for (int nt = 0; nt < 2; nt++) {
            int nl = w * 32 + nt * 16 + l16;
            bH[nt] = *(const bf16x8*)&((const unsigned short*)LfH[buf])[nl * 40 + q * 8];
            bL[nt] = *(const bf16x8*)&((const unsigned short*)LfL[buf])[nl * 40 + q * 8];
        }
#pragma unroll
        for (int mt = 0; mt < 4; mt++)
#pragma unroll
            for (int nt = 0; nt < 2; nt++) {
                acc[mt][nt] = __builtin_amdgcn_mfma_f32_16x16x32_bf16(aH[mt], bH[nt], acc[mt][nt], 0, 0, 0);
                acc[mt][nt] = __builtin_amdgcn_mfma_f32_16x16x32_bf16(aH[mt], bL[nt], acc[mt][nt], 0, 0, 0);
                acc[mt][nt] = __builtin_amdgcn_mfma_f32_16x16x32_bf16(aL[mt], bH[nt], acc[mt][nt], 0, 0, 0);
            }
    };

    sload(0);
    sstore(0);
    __syncthreads();
    int cur = 0;
    for (int d0 = 0; d0 < DF_ - 32; d0 += 32) {
        sload(d0 + 32);        // issue next-tile loads (consumed below, before barrier)
        scomp(cur);            // MFMA on current buffer hides the load latency
        sstore(cur ^ 1);       // vmcnt wait lands here, after the MFMAs
        __syncthreads();
        cur ^= 1;
    }
    scomp(cur);                // last tile: no barrier needed

    float* sb = s + (size_t)b * T_ * N_;
#pragma unroll
    for (int mt = 0; mt < 4; mt++)
#pragma unroll
        for (int nt = 0; nt < 2; nt++)
#pragma unroll
            for (int r = 0; r < 4; r++) {
                int t = mt * 16 + q * 4 + r;
                int n = nblk + w * 32 + nt * 16 + l16;
                sb[(size_t)t * N_ + n] = acc[mt][nt][r];
            }
}

// ---------------------------------------------------------------------------
// softmax over n -> bf16 alpha.  One wave per row: no LDS, no barriers.
// grid = B*T/4 blocks of 256 threads (4 independent waves).
// ---------------------------------------------------------------------------
__global__ __launch_bounds__(256) void softmax_k(const float* __restrict__ s,
                                                 unsigned short* __restrict__ alpha,
                                                 const float* __restrict__ gptr) {
    const float g = gptr[0];
    const int row_id = blockIdx.x * 4 + (threadIdx.x >> 6);
    const int lane = threadIdx.x & 63;
    const float* row = s + (size_t)row_id * N_;
    unsigned short* arow = alpha + (size_t)row_id * N_;

    float4 x[4];
#pragma unroll
    for (int i = 0; i < 4; i++) {
        x[i] = *(const float4*)(row + i * 256 + lane * 4);   // perfectly coalesced
        x[i].x *= g; x[i].y *= g; x[i].z *= g; x[i].w *= g;
    }
    float m = x[0].x;
#pragma unroll
    for (int i = 0; i < 4; i++)
        m = fmaxf(m, fmaxf(fmaxf(x[i].x, x[i].y), fmaxf(x[i].z, x[i].w)));
#pragma unroll
    for (int off = 32; off > 0; off >>= 1) m = fmaxf(m, __shfl_xor(m, off, 64));

    float ev[16];
    float sum = 0.f;
#pragma unroll
    for (int i = 0; i < 4; i++) {
        ev[i * 4 + 0] = __expf(x[i].x - m);
        ev[i * 4 + 1] = __expf(x[i].y - m);
        ev[i * 4 + 2] = __expf(x[i].z - m);
        ev[i * 4 + 3] = __expf(x[i].w - m);
        sum += ev[i * 4 + 0] + ev[i * 4 + 1] + ev[i * 4 + 2] + ev[i * 4 + 3];
    }
#pragma unroll
    for (int off = 32; off > 0; off >>= 1) sum += __shfl_xor(sum, off, 64);
    float inv = 1.f / sum;
#pragma unroll
    for (int i = 0; i < 4; i++) {
        unsigned p0 = (unsigned)bf_rne(ev[i * 4 + 0] * inv) | ((unsigned)bf_rne(ev[i * 4 + 1] * inv) << 16);
        unsigned p1 = (unsigned)bf_rne(ev[i * 4 + 2] * inv) | ((unsigned)bf_rne(ev[i * 4 + 3] * inv) << 16);
        uint2 o; o.x = p0; o.y = p1;
        *(uint2*)&arow[i * 256 + lane * 4] = o;
    }
}

// ---------------------------------------------------------------------------
// gemm_h: hT[t][d] = sum_n f[d][n]*alpha[t][n]   (plain bf16)
// grid (DF/64, B) = 768 blocks, tile [64d x 64t], BK=64.
// DOUBLE-BUFFERED LDS, one barrier per K-step (same scheme as gemm_s).
// ---------------------------------------------------------------------------
__global__ __launch_bounds__(256, 2) void gemm_h(const float* __restrict__ f,
                                                 const unsigned short* __restrict__ alpha,
                                                 unsigned short* __restrict__ hT) {
    __shared__ unsigned short Lf[2][64 * 72];
    __shared__ unsigned short La[2][64 * 72];
    const int dblk = blockIdx.x * 64;
    const int b = blockIdx.y;
    const int tid = threadIdx.x;
    const int lane = tid & 63, w = tid >> 6, q = lane >> 4, l16 = lane & 15;

    const float* fb = f + (size_t)b * DF_ * N_;
    const unsigned short* ab = alpha + (size_t)b * T_ * N_;

    f32x4 acc[4];
#pragma unroll
    for (int i = 0; i < 4; i++) acc[i] = (f32x4)(0.f);

    const int fr_ = tid >> 2, fc = tid & 3;
    const float* frbase = fb + (size_t)(dblk + fr_) * N_ + fc * 16;
    const unsigned short* abase = ab + (size_t)fr_ * N_ + fc * 16;

    float4 pf0, pf1, pf2, pf3;
    uint4 pa0, pa1;

    auto hload = [&](int n0) {
        const float* fp = frbase + n0;
        pf0 = *(const float4*)&fp[0];
        pf1 = *(const float4*)&fp[4];
        pf2 = *(const float4*)&fp[8];
        pf3 = *(const float4*)&fp[12];
        pa0 = *(const uint4*)&abase[n0];
        pa1 = *(const uint4*)&abase[n0 + 8];
    };
    auto hstore = [&](int buf) {
        const float4 fx[4] = {pf0, pf1, pf2, pf3};
#pragma unroll
        for (int i = 0; i < 4; i++) {
            float4 x = fx[i];
            unsigned p0 = (unsigned)bf_rne(x.x) | ((unsigned)bf_rne(x.y) << 16);
            unsigned p1 = (unsigned)bf_rne(x.z) | ((unsigned)bf_rne(x.w) << 16);
            uint2 o; o.x = p0; o.y = p1;
            *(uint2*)&Lf[buf][fr_ * 72 + fc * 16 + i * 4] = o;
        }
        *(uint4*)&La[buf][fr_ * 72 + fc * 16]     = pa0;
        *(uint4*)&La[buf][fr_ * 72 + fc * 16 + 8] = pa1;
    };
    auto hcomp = [&](int buf) {
        bf16x8 af[2], bb[4][2];
#pragma unroll
        for (int kk = 0; kk < 2; kk++)
            af[kk] = *(const bf16x8*)&Lf[buf][(w * 16 + l16) * 72 + kk * 32 + q * 8];
#pragma unroll
        for (int nt = 0; nt < 4; nt++)
#pragma unroll
            for (int kk = 0; kk < 2; kk++)
                bb[nt][kk] = *(const bf16x8*)&La[buf][(nt * 16 + l16) * 72 + kk * 32 + q * 8];
#pragma unroll
        for (int nt = 0; nt < 4; nt++)
#pragma unroll
            for (int kk = 0; kk < 2; kk++)
                acc[nt] = __builtin_amdgcn_mfma_f32_16x16x32_bf16(af[kk], bb[nt][kk], acc[nt], 0, 0, 0);
    };

    hload(0);
    hstore(0);
    __syncthreads();
    int cur = 0;
    for (int n0 = 0; n0 < N_ - 64; n0 += 64) {
        hload(n0 + 64);        // issue next-tile loads
        hcomp(cur);            // compute current buffer
        hstore(cur ^ 1);       // consume loads after MFMAs
        __syncthreads();
        cur ^= 1;
    }
    hcomp(cur);

    unsigned short* hb = hT + (size_t)b * T_ * DF_;
#pragma unroll
    for (int nt = 0; nt < 4; nt++)
#pragma unroll
        for (int r = 0; r < 4; r++) {
            int d = dblk + w * 16 + q * 4 + r;
            int t = nt * 16 + l16;
            hb[(size_t)t * DF_ + d] = bf_rne(acc[nt][r]);
        }
}

// ---------------------------------------------------------------------------
// gemm_c: c[k][t] = sum_d W[d][k]*h[d][t] + bias[k]   (plain bf16)
// grid (K/64, B) = 256 blocks, tile [64k x 64t], BK=64.  (round-0 form)
// ---------------------------------------------------------------------------
__global__ __launch_bounds__(256, 2) void gemm_c(const unsigned short* __restrict__ WT_hi,
                                                 const unsigned short* __restrict__ hT,
                                                 const float* __restrict__ bias,
                                                 float* __restrict__ c) {
    __shared__ unsigned short LW[64 * 72];
    __shared__ unsigned short Lh[64 * 72];
    const int kblk = blockIdx.x * 64;
    const int b = blockIdx.y;
    const int tid = threadIdx.x;
    const int lane = tid & 63, w = tid >> 6, q = lane >> 4, l16 = lane & 15;

    const unsigned short* hb = hT + (size_t)b * T_ * DF_;

    f32x4 acc[4];
#pragma unroll
    for (int i = 0; i < 4; i++) acc[i] = (f32x4)(0.f);

    for (int d0 = 0; d0 < DF_; d0 += 64) {
#pragma unroll
        for (int l = 0; l < 2; l++) {
            int idx = tid * 2 + l;
            int r = idx >> 3, c8 = (idx & 7) * 8;
            *(uint4*)&LW[r * 72 + c8] = *(const uint4*)&WT_hi[(size_t)(kblk + r) * DF_ + d0 + c8];
            *(uint4*)&Lh[r * 72 + c8] = *(const uint4*)&hb[(size_t)r * DF_ + d0 + c8];
        }
        __syncthreads();
        bf16x8 aw[2], bh[4][2];
#pragma unroll
        for (int kk = 0; kk < 2; kk++)
            aw[kk] = *(const bf16x8*)&LW[(w * 16 + l16) * 72 + kk * 32 + q * 8];
#pragma unroll
        for (int nt = 0; nt < 4; nt++)
#pragma unroll
            for (int kk = 0; kk < 2; kk++)
                bh[nt][kk] = *(const bf16x8*)&Lh[(nt * 16 + l16) * 72 + kk * 32 + q * 8];
#pragma unroll
        for (int nt = 0; nt < 4; nt++)
#pragma unroll
            for (int kk = 0; kk < 2; kk++)
                acc[nt] = __builtin_amdgcn_mfma_f32_16x16x32_bf16(aw[kk], bh[nt][kk], acc[nt], 0, 0, 0);
        __syncthreads();
    }

    float* cb = c + (size_t)b * K_ * T_;
#pragma unroll
    for (int nt = 0; nt < 4; nt++)
#pragma unroll
        for (int r = 0; r < 4; r++) {
            int k = kblk + w * 16 + q * 4 + r;
            int t = nt * 16 + l16;
            cb[(size_t)k * T_ + t] = acc[nt][r] + bias[k];
        }
}

// ---------------------------------------------------------------------------
// cos_k: cos[b,i,j] = <c[:,i], e[:,j]> / (|c[:,i]| |e[:,j]|)
// grid (T/4, B), 256 threads: wave iq handles row i = bx*4+iq.
// ---------------------------------------------------------------------------
__global__ __launch_bounds__(256) void cos_k(const float* __restrict__ c,
                                             const float* __restrict__ e,
                                             float* __restrict__ out) {
    const int iq = threadIdx.x >> 6;
    const int i = blockIdx.x * 4 + iq;
    const int b = blockIdx.y;
    const int j = threadIdx.x & 63;
    const float* cb = c + (size_t)b * K_ * T_;
    const float* eb = e + (size_t)b * K_ * T_;

    float dot = 0.f, se = 0.f, sc = 0.f;
#pragma unroll 8
    for (int k = 0; k < K_; k++) {
        float cv = cb[(size_t)k * T_ + i];
        float ev = eb[(size_t)k * T_ + j];
        dot += cv * ev;
        se  += ev * ev;
        sc  += cv * cv;
    }
    out[((size_t)b * T_ + i) * T_ + j] = dot * rsqrtf(sc * se);
}

// ---------------------------------------------------------------------------
extern "C" void kernel_launch(void* const* d_in, const int* in_sizes, int n_in,
                              void* d_out, int out_size, void* d_ws, size_t ws_size,
                              hipStream_t stream) {
    const float* e     = (const float*)d_in[0];  // [B,K,T]
    const float* f     = (const float*)d_in[1];  // [B,DF,N]
    const float* gamma = (const float*)d_in[2];
    const float* W     = (const float*)d_in[3];  // [DF,K]
    const float* bias  = (const float*)d_in[4];  // [K]
    float* out = (float*)d_out;                  // [B,T,T]

    char* p = (char*)d_ws;
    unsigned short* W_hi  = (unsigned short*)p; p += (size_t)DF_ * K_ * 2;
    unsigned short* W_lo  = (unsigned short*)p; p += (size_t)DF_ * K_ * 2;
    unsigned short* WT_hi = (unsigned short*)p; p += (size_t)DF_ * K_ * 2;
    unsigned short* eT_hi = (unsigned short*)p; p += (size_t)B_ * T_ * K_ * 2;
    unsigned short* eT_lo = (unsigned short*)p; p += (size_t)B_ * T_ * K_ * 2;
    unsigned short* gT_hi = (unsigned short*)p; p += (size_t)B_ * T_ * DF_ * 2;
    unsigned short* gT_lo = (unsigned short*)p; p += (size_t)B_ * T_ * DF_ * 2;
    float*          s     = (float*)p;          p += (size_t)B_ * T_ * N_ * 4;
    unsigned short* alpha = (unsigned short*)p; p += (size_t)B_ * T_ * N_ * 2;
    unsigned short* hT    = (unsigned short*)p; p += (size_t)B_ * T_ * DF_ * 2;
    float*          c     = (float*)p;          p += (size_t)B_ * K_ * T_ * 4;

    prep_we <<<dim3(DF_ + 256),      256, 0, stream>>>(W, e, W_hi, W_lo, WT_hi, eT_hi, eT_lo);
    gemm_g  <<<dim3(DF_ / 64, B_),   256, 0, stream>>>(eT_hi, eT_lo, W_hi, W_lo, gT_hi, gT_lo);
    gemm_s  <<<dim3(512),            256, 0, stream>>>(gT_hi, gT_lo, f, s);
    softmax_k<<<dim3(B_ * T_ / 4),   256, 0, stream>>>(s, alpha, gamma);
    gemm_h  <<<dim3(DF_ / 64, B_),   256, 0, stream>>>(f, alpha, hT);
    gemm_c  <<<dim3(K_ / 64, B_),    256, 0, stream>>>(WT_hi, hT, bias, c);
    cos_k   <<<dim3(T_ / 4, B_),     256, 0, stream>>>(c, e, out);
}